// Round 1
// baseline (1626.688 us; speedup 1.0000x reference)
//
#include <hip/hip_runtime.h>
#include <math.h>

// Problem: B=4, C=192, H=W=256 -> N=65536, heads=8, Ch=24
//
// Algebraic restructure (this round): Q,K are only consumed through
// row-reductions over N, so everything factors through S = X X^T:
//   S_b    = X_b X_b^T (192x192)                      [K1s]
//   T = Wq_h S, U = Wk_h S;  ssq_q[c] = T[c].Wq[c];   [K2a]
//   G_h = T Wk_h^T;  attn = softmax(G*temp/(|q||k|))  [K2a]
//   M_b  = W_out * blockdiag(attn)                    [K2a]
//   P_b  = M_b * W_v                                  [K2b]
//   out  = P_b * x_b                                  [K3]
//
// ws layout (floats):
//   spart : 4 slices * 4 b * 36864 = 589824   (atomic-reduced partial S)
//   M     : 4 * 192 * 192          = 147456
//   P     : 4 * 192 * 192          = 147456

#define L2EPS 1e-12f

// ---------------------------------------------------------------- K1s
// S_b = X_b X_b^T, grid (128, 4), 256 threads, 2 blocks/CU.
// Each block: 512 columns (8 chunks of 64). Thread tile 12x12 (144 acc).
// LDS chunk stored TRANSPOSED (Xs[n][row], row-pad 196) so the compute
// loop reads both operands as conflict-free ds_read_b128 over rows
// (bank pos for xi: 4 distinct quads broadcast; xj: 2-way = free).
// Staging does an in-register 4x4 transpose -> f4 LDS writes at BW floor.
__global__ __launch_bounds__(256, 2) void k1s_xxt(
    const float* __restrict__ x, float* __restrict__ spart)
{
  __shared__ float Xs[64][196];
  const int t = threadIdx.x;
  const int b = blockIdx.y;
  const int ti = t >> 4, tj = t & 15;
  const int i0 = ti * 12, j0 = tj * 12;
  const int nbase = blockIdx.x * 512;
  const float* xb = x + (size_t)b * 192 * 65536;

  float acc[12][12];
#pragma unroll
  for (int i = 0; i < 12; ++i)
#pragma unroll
    for (int j = 0; j < 12; ++j) acc[i][j] = 0.f;

  for (int ch = 0; ch < 8; ++ch) {
    const int n0 = nbase + ch * 64;
    // stage 192 rows x 64 cols, transposed: 768 groups of 4x4
#pragma unroll
    for (int u = 0; u < 3; ++u) {
      const int g = t + 256 * u;      // 0..767
      const int rq = g >> 4;          // row quad 0..47
      const int n4 = g & 15;          // col quad 0..15
      const float* src = &xb[(size_t)(rq * 4) * 65536 + n0 + n4 * 4];
      const float4 v0 = *(const float4*)(src);
      const float4 v1 = *(const float4*)(src + 65536);
      const float4 v2 = *(const float4*)(src + 2 * 65536);
      const float4 v3 = *(const float4*)(src + 3 * 65536);
      *(float4*)&Xs[n4 * 4 + 0][rq * 4] = make_float4(v0.x, v1.x, v2.x, v3.x);
      *(float4*)&Xs[n4 * 4 + 1][rq * 4] = make_float4(v0.y, v1.y, v2.y, v3.y);
      *(float4*)&Xs[n4 * 4 + 2][rq * 4] = make_float4(v0.z, v1.z, v2.z, v3.z);
      *(float4*)&Xs[n4 * 4 + 3][rq * 4] = make_float4(v0.w, v1.w, v2.w, v3.w);
    }
    __syncthreads();
#pragma unroll 2
    for (int n = 0; n < 64; ++n) {
      const float4 a0 = *(const float4*)&Xs[n][i0];
      const float4 a1 = *(const float4*)&Xs[n][i0 + 4];
      const float4 a2 = *(const float4*)&Xs[n][i0 + 8];
      const float4 c0 = *(const float4*)&Xs[n][j0];
      const float4 c1 = *(const float4*)&Xs[n][j0 + 4];
      const float4 c2 = *(const float4*)&Xs[n][j0 + 8];
      const float xi[12] = {a0.x, a0.y, a0.z, a0.w, a1.x, a1.y, a1.z, a1.w,
                            a2.x, a2.y, a2.z, a2.w};
      const float xj[12] = {c0.x, c0.y, c0.z, c0.w, c1.x, c1.y, c1.z, c1.w,
                            c2.x, c2.y, c2.z, c2.w};
#pragma unroll
      for (int ii = 0; ii < 12; ++ii)
#pragma unroll
        for (int jj = 0; jj < 12; ++jj)
          acc[ii][jj] += xi[ii] * xj[jj];
    }
    __syncthreads();
  }

  // flush: 4-slice partial reduction (32 blocks contend per slice cell)
  const int slice = blockIdx.x & 3;
  float* sd = spart + (size_t)(slice * 4 + b) * 36864;
#pragma unroll
  for (int ii = 0; ii < 12; ++ii)
#pragma unroll
    for (int jj = 0; jj < 12; ++jj)
      atomicAdd(&sd[(i0 + ii) * 192 + j0 + jj], acc[ii][jj]);
}

// ---------------------------------------------------------------- K2a
// grid (8, 4): one block per (h, b). From S: T=Wq_h S, U=Wk_h S,
// ssq from diag, G = T Wk_h^T, softmax -> A, M = W_out_h @ A.
// Symmetry trick: T[r][j] = sum_i W[r][i]*S[j][i] -- reads S rows
// (natural row-major, coalesced) instead of columns. 6x6 thread tile,
// rows strided by 8, cols strided by 32 (keeps LDS reads at bank floor).
__global__ __launch_bounds__(256) void k2a_softmax_m(
    const float* __restrict__ spart, const float* __restrict__ wqkv,
    const float* __restrict__ temp, const float* __restrict__ wout,
    float* __restrict__ M)
{
  __shared__ float Ws[48][196];   // rows 0..23 = Wq_h, 24..47 = Wk_h
  __shared__ float Ss[192][68];   // Ss[j][il] = S[j][i0+il] (i-chunk of 64)
  __shared__ float Ts[48][196];   // rows 0..23 = T = Wq S, 24..47 = U = Wk S
  __shared__ float Gs[24][24];
  __shared__ float As[24][24];
  __shared__ float ssqs[48];
  __shared__ float rqs[24], rks[24];

  const int t = threadIdx.x;
  const int h = blockIdx.x;
  const int b = blockIdx.y;

  // load Ws: 48 rows x 192 = 2304 f4
#pragma unroll
  for (int u = 0; u < 9; ++u) {
    const int e4 = t + 256 * u;
    const int r = e4 / 48;          // 0..47
    const int c4 = e4 % 48;
    const int gr = (r < 24) ? (h * 24 + r) : (192 + h * 24 + (r - 24));
    *(float4*)&Ws[r][c4 * 4] = *(const float4*)&wqkv[(size_t)gr * 192 + c4 * 4];
  }

  // T/U: thread (rg,jg) owns rows rg+8k (k<6), cols jg+32m (m<6)
  const int rg = t >> 5;            // 0..7
  const int jg = t & 31;            // 0..31
  float tacc[6][6];
#pragma unroll
  for (int k = 0; k < 6; ++k)
#pragma unroll
    for (int m = 0; m < 6; ++m) tacc[k][m] = 0.f;

  for (int ic = 0; ic < 3; ++ic) {
    const int i0 = ic * 64;
    __syncthreads();                 // protect Ss vs previous chunk readers
    // reduce 4 slices while staging: Ss[j][il] = S[j][i0+il]
#pragma unroll
    for (int u = 0; u < 12; ++u) {
      const int e4 = t + 256 * u;
      const int j = e4 >> 4;         // 0..191
      const int il4 = e4 & 15;       // 0..15
      const size_t off = (size_t)j * 192 + i0 + il4 * 4;
      float4 s = *(const float4*)&spart[(size_t)b * 36864 + off];
      const float4 s1 = *(const float4*)&spart[(size_t)(4 + b) * 36864 + off];
      const float4 s2 = *(const float4*)&spart[(size_t)(8 + b) * 36864 + off];
      const float4 s3 = *(const float4*)&spart[(size_t)(12 + b) * 36864 + off];
      s.x += s1.x + s2.x + s3.x;  s.y += s1.y + s2.y + s3.y;
      s.z += s1.z + s2.z + s3.z;  s.w += s1.w + s2.w + s3.w;
      *(float4*)&Ss[j][il4 * 4] = s;
    }
    __syncthreads();
#pragma unroll
    for (int il4 = 0; il4 < 16; ++il4) {
      float4 w4[6], s4[6];
#pragma unroll
      for (int k = 0; k < 6; ++k)
        w4[k] = *(const float4*)&Ws[rg + 8 * k][i0 + il4 * 4];
#pragma unroll
      for (int m = 0; m < 6; ++m)
        s4[m] = *(const float4*)&Ss[jg + 32 * m][il4 * 4];
#pragma unroll
      for (int k = 0; k < 6; ++k)
#pragma unroll
        for (int m = 0; m < 6; ++m)
          tacc[k][m] += w4[k].x * s4[m].x + w4[k].y * s4[m].y +
                        w4[k].z * s4[m].z + w4[k].w * s4[m].w;
    }
  }
#pragma unroll
  for (int k = 0; k < 6; ++k)
#pragma unroll
    for (int m = 0; m < 6; ++m)
      Ts[rg + 8 * k][jg + 32 * m] = tacc[k][m];
  __syncthreads();

  // ssq: row r of [T;U] dotted with row r of [Wq;Wk]; 4 threads/row
  if (t < 192) {
    const int r = t >> 2, q = t & 3;
    float s = 0.f;
#pragma unroll
    for (int u = 0; u < 12; ++u) {
      const int j4 = q * 12 + u;
      const float4 tv = *(const float4*)&Ts[r][j4 * 4];
      const float4 wv = *(const float4*)&Ws[r][j4 * 4];
      s += tv.x * wv.x + tv.y * wv.y + tv.z * wv.z + tv.w * wv.w;
    }
    s += __shfl_xor(s, 1);
    s += __shfl_xor(s, 2);
    if (q == 0) ssqs[r] = s;
  }
  // G[c][d] = T[c] . Wk[d]
#pragma unroll
  for (int u = 0; u < 3; ++u) {
    const int idx = t + 256 * u;
    if (idx < 576) {
      const int c = idx / 24, d = idx % 24;
      float s = 0.f;
#pragma unroll
      for (int j4 = 0; j4 < 48; ++j4) {
        const float4 tv = *(const float4*)&Ts[c][j4 * 4];
        const float4 wv = *(const float4*)&Ws[24 + d][j4 * 4];
        s += tv.x * wv.x + tv.y * wv.y + tv.z * wv.z + tv.w * wv.w;
      }
      Gs[c][d] = s;
    }
  }
  __syncthreads();
  if (t < 24) rqs[t] = 1.f / fmaxf(sqrtf(ssqs[t]), L2EPS);
  else if (t >= 32 && t < 56) rks[t - 32] = 1.f / fmaxf(sqrtf(ssqs[24 + t - 32]), L2EPS);
  __syncthreads();

  if (t < 24) {
    const float tempv = temp[h];
    const float rqc = rqs[t];
    float v[24];
    float m = -1e30f;
#pragma unroll
    for (int d = 0; d < 24; ++d) {
      v[d] = Gs[t][d] * tempv * rqc * rks[d];
      m = fmaxf(m, v[d]);
    }
    float s = 0.f;
#pragma unroll
    for (int d = 0; d < 24; ++d) { v[d] = expf(v[d] - m); s += v[d]; }
    const float inv = 1.f / s;
#pragma unroll
    for (int d = 0; d < 24; ++d) As[t][d] = v[d] * inv;
  }
  __syncthreads();

  // M[o][h*24+j] = sum_i wout[o][h*24+i] * As[i][j]; 192*24 = 4608 = 256*18
#pragma unroll
  for (int u = 0; u < 18; ++u) {
    const int p = t + 256 * u;
    const int o = p / 24, j = p % 24;
    float s = 0.f;
#pragma unroll
    for (int i = 0; i < 24; ++i)
      s += wout[o * 192 + h * 24 + i] * As[i][j];
    M[((size_t)b * 192 + o) * 192 + h * 24 + j] = s;
  }
}

// ---------------------------------------------------------------- K2b
// grid (24, 4): P_b = M_b @ Wv  (192x192 @ 192x192), 8 rows per block.
__global__ __launch_bounds__(256) void k2b_p(
    const float* __restrict__ M, const float* __restrict__ wqkv,
    float* __restrict__ P)
{
  __shared__ float Ms[8][192];
  const int t = threadIdx.x;
  const int r0 = blockIdx.x * 8;
  const int b = blockIdx.y;
  for (int e = t; e < 1536; e += 256)
    (&Ms[0][0])[e] = M[((size_t)b * 192 + r0) * 192 + e];
  __syncthreads();
  const float4* wv4 = (const float4*)(wqkv + 384 * 192);
#pragma unroll
  for (int u = 0; u < 2; ++u) {
    const int idx4 = t + 256 * u;
    if (idx4 < 384) {
      const int ol = idx4 / 48, c4 = idx4 % 48;
      float4 a = make_float4(0.f, 0.f, 0.f, 0.f);
      for (int c = 0; c < 192; ++c) {
        const float m = Ms[ol][c];
        const float4 w = wv4[c * 48 + c4];
        a.x += m * w.x; a.y += m * w.y; a.z += m * w.z; a.w += m * w.w;
      }
      ((float4*)P)[((size_t)b * 192 + r0 + ol) * 48 + c4] = a;
    }
  }
}

// ---------------------------------------------------------------- K3
// grid (1024, 4): out_b = P_b @ x_b. Block: 192 rows x 64 cols. (unchanged)
__global__ __launch_bounds__(256, 2) void k3_out(
    const float* __restrict__ P, const float* __restrict__ x,
    float* __restrict__ out)
{
  __shared__ float Xs[16][68];
  __shared__ float Ps[16][196];
  const int t = threadIdx.x;
  const int b = blockIdx.y;
  const int n0 = blockIdx.x * 64;
  const int cg = t & 15;          // 16 col groups * 4 = 64
  const int rowg = t >> 4;        // 16 row groups * 12 = 192
  const int rowbase = rowg * 12;
  const float* xb = x + (size_t)b * 192 * 65536;
  const float4* Pb4 = (const float4*)(P + (size_t)b * 36864);

  float acc[12][4];
#pragma unroll
  for (int i = 0; i < 12; ++i)
#pragma unroll
    for (int j = 0; j < 4; ++j) acc[i][j] = 0.f;

  for (int kb = 0; kb < 12; ++kb) {
    {
      const int kl = t >> 4, n4 = t & 15;
      *(float4*)&Xs[kl][n4 * 4] =
          *(const float4*)&xb[(size_t)(kb * 16 + kl) * 65536 + n0 + n4 * 4];
    }
#pragma unroll
    for (int i = 0; i < 3; ++i) {        // 192 rows * 4 f4 = 768 f4
      const int e4 = t + i * 256;
      const int r = e4 >> 2, kq = e4 & 3;
      const float4 w = Pb4[r * 48 + kb * 4 + kq];
      Ps[kq * 4 + 0][r] = w.x; Ps[kq * 4 + 1][r] = w.y;
      Ps[kq * 4 + 2][r] = w.z; Ps[kq * 4 + 3][r] = w.w;
    }
    __syncthreads();
#pragma unroll
    for (int k = 0; k < 16; ++k) {
      const float4 xv = *(const float4*)&Xs[k][cg * 4];
      const float xa[4] = {xv.x, xv.y, xv.z, xv.w};
#pragma unroll
      for (int i3 = 0; i3 < 3; ++i3) {
        const float4 wv = *(const float4*)&Ps[k][rowbase + i3 * 4];
        const float wa[4] = {wv.x, wv.y, wv.z, wv.w};
#pragma unroll
        for (int ii = 0; ii < 4; ++ii)
#pragma unroll
          for (int j = 0; j < 4; ++j)
            acc[i3 * 4 + ii][j] += wa[ii] * xa[j];
      }
    }
    __syncthreads();
  }
  float* ob = out + ((size_t)b * 192 + rowbase) * 65536 + n0 + cg * 4;
#pragma unroll
  for (int i = 0; i < 12; ++i)
    *(float4*)&ob[(size_t)i * 65536] =
        make_float4(acc[i][0], acc[i][1], acc[i][2], acc[i][3]);
}

// ---------------------------------------------------------------- launch
extern "C" void kernel_launch(void* const* d_in, const int* in_sizes, int n_in,
                              void* d_out, int out_size, void* d_ws, size_t ws_size,
                              hipStream_t stream) {
  const float* x    = (const float*)d_in[0];
  const float* wqkv = (const float*)d_in[1];
  const float* wout = (const float*)d_in[2];
  const float* temp = (const float*)d_in[3];
  float* out = (float*)d_out;

  float* ws    = (float*)d_ws;
  float* spart = ws;               // 589824 floats (4 slices * 4 b * 36864)
  float* M     = ws + 589824;      // 147456
  float* P     = ws + 737280;      // 147456

  // zero the atomic S-partials; ws is poisoned before every launch
  hipMemsetAsync(d_ws, 0, (size_t)589824 * sizeof(float), stream);

  k1s_xxt<<<dim3(128, 4), 256, 0, stream>>>(x, spart);
  k2a_softmax_m<<<dim3(8, 4), 256, 0, stream>>>(spart, wqkv, temp, wout, M);
  k2b_p<<<dim3(24, 4), 256, 0, stream>>>(M, wqkv, P);
  k3_out<<<dim3(1024, 4), 256, 0, stream>>>(P, x, out);
}

// Round 2
// 845.301 us; speedup vs baseline: 1.9244x; 1.9244x over previous
//
#include <hip/hip_runtime.h>
#include <math.h>

// Problem: B=4, C=192, H=W=256 -> N=65536, heads=8, Ch=24
//
// Factorization through S = X X^T (Q,K only consumed via row-reductions):
//   S_b    = X_b X_b^T (192x192)                      [K1s (+Kred)]
//   T = Wq_h S;  ssq_q[c] = T[c].Wq[c]  (sym. trick)  [K2a]
//   G_h = T Wk_h^T;  attn = softmax(G*temp/(|q||k|))  [K2a]
//   M_b  = W_out * blockdiag(attn)                    [K2a]
//   P_b  = M_b * W_v                                  [K2b]
//   out  = P_b * x_b                                  [K3]
//
// Round-2 changes:
//  * k1s: 384 threads, 12x8 thread tile (96 acc, fits < launch_bounds(384,3)
//    cap of ~170 VGPR -> no scratch spill; round-1's 256thr/12x12 forced a
//    144-reg accumulator, VGPR_Count=116 proved it spilled, VALUBusy 12%).
//  * No atomics on the main path: exclusive per-block slabs + reduce kernel
//    (round-1: 18.9M device-scope atomicAdds -> 576MB of 32B HBM sector
//    writes). Runtime fallback to the atomic 4-slice plan if ws is small.
//  * k3: same 12x8 tile treatment (was 12x4, LDS-issue-bound ~440us).

#define L2EPS 1e-12f

// acc[rr][0..7] += av * {c0,c1}
#define ROW8(rr, av)                                                     \
  acc[rr][0] += (av) * c0.x; acc[rr][1] += (av) * c0.y;                  \
  acc[rr][2] += (av) * c0.z; acc[rr][3] += (av) * c0.w;                  \
  acc[rr][4] += (av) * c1.x; acc[rr][5] += (av) * c1.y;                  \
  acc[rr][6] += (av) * c1.z; acc[rr][7] += (av) * c1.w;

// ---------------------------------------------------------------- K1s
// S_b = X_b X_b^T. grid (128, 4), 384 threads (6 waves), 2 blocks/CU.
// Block: 512 columns (8 chunks of 64). Thread tile 12x8 -> 96 acc.
// LDS chunk transposed (Xs[n][row], pad 196): compute reads are b128,
// 2-way bank aliasing max (free). Staging = in-register 4x4 transpose.
// excl=1: block writes exclusive slab (coalesced, thread-linear layout).
// excl=0: atomicAdd into 4-slice natural-layout spart (fallback).
__global__ __launch_bounds__(384, 3) void k1s_xxt(
    const float* __restrict__ x, float* __restrict__ spart, const int excl)
{
  __shared__ float Xs[64][196];
  const int t = threadIdx.x;          // 0..383
  const int b = blockIdx.y;
  const int bx = blockIdx.x;          // 0..127
  const int ti = t / 24;              // 0..15 -> 12-row strip
  const int tj = t % 24;              // 0..23 -> 8-col strip
  const int i0 = ti * 12, j0 = tj * 8;
  const int nbase = bx * 512;
  const float* xb = x + (size_t)b * 192 * 65536;

  float acc[12][8];
#pragma unroll
  for (int i = 0; i < 12; ++i)
#pragma unroll
    for (int j = 0; j < 8; ++j) acc[i][j] = 0.f;

  for (int ch = 0; ch < 8; ++ch) {
    const int n0 = nbase + ch * 64;
    // stage 192 rows x 64 cols transposed: 768 4x4 groups, 2/thread
#pragma unroll
    for (int u = 0; u < 2; ++u) {
      const int g = t + 384 * u;      // 0..767
      const int rq = g >> 4;          // row quad 0..47
      const int n4 = g & 15;          // col quad 0..15
      const float* src = &xb[(size_t)(rq * 4) * 65536 + n0 + n4 * 4];
      const float4 v0 = *(const float4*)(src);
      const float4 v1 = *(const float4*)(src + 65536);
      const float4 v2 = *(const float4*)(src + 2 * 65536);
      const float4 v3 = *(const float4*)(src + 3 * 65536);
      *(float4*)&Xs[n4 * 4 + 0][rq * 4] = make_float4(v0.x, v1.x, v2.x, v3.x);
      *(float4*)&Xs[n4 * 4 + 1][rq * 4] = make_float4(v0.y, v1.y, v2.y, v3.y);
      *(float4*)&Xs[n4 * 4 + 2][rq * 4] = make_float4(v0.z, v1.z, v2.z, v3.z);
      *(float4*)&Xs[n4 * 4 + 3][rq * 4] = make_float4(v0.w, v1.w, v2.w, v3.w);
    }
    __syncthreads();
#pragma unroll 2
    for (int n = 0; n < 64; ++n) {
      const float4 a0 = *(const float4*)&Xs[n][i0];
      const float4 a1 = *(const float4*)&Xs[n][i0 + 4];
      const float4 a2 = *(const float4*)&Xs[n][i0 + 8];
      const float4 c0 = *(const float4*)&Xs[n][j0];
      const float4 c1 = *(const float4*)&Xs[n][j0 + 4];
      ROW8(0, a0.x)  ROW8(1, a0.y)  ROW8(2, a0.z)  ROW8(3, a0.w)
      ROW8(4, a1.x)  ROW8(5, a1.y)  ROW8(6, a1.z)  ROW8(7, a1.w)
      ROW8(8, a2.x)  ROW8(9, a2.y)  ROW8(10, a2.z) ROW8(11, a2.w)
    }
    __syncthreads();
  }

  if (excl) {
    // exclusive slab, thread-linear layout: slab[e*384 + t] = acc[e]
    float* sd = spart + (size_t)(b * 128 + bx) * 36864;
#pragma unroll
    for (int ii = 0; ii < 12; ++ii)
#pragma unroll
      for (int jj = 0; jj < 8; ++jj)
        sd[(ii * 8 + jj) * 384 + t] = acc[ii][jj];
  } else {
    // fallback: 4-slice atomic reduction, natural (i,j) layout
    float* sd = spart + (size_t)((bx & 3) * 4 + b) * 36864;
#pragma unroll
    for (int ii = 0; ii < 12; ++ii)
#pragma unroll
      for (int jj = 0; jj < 8; ++jj)
        atomicAdd(&sd[(i0 + ii) * 192 + (j0 + jj)], acc[ii][jj]);
  }
}

// ---------------------------------------------------------------- Kred
// Reduce 128 exclusive slabs -> S[b][192][192] (natural layout).
// grid (144, 4), 256 thr: thread = one cell, coalesced across slabs.
__global__ __launch_bounds__(256) void kreduce(
    const float* __restrict__ spart, float* __restrict__ S)
{
  const int t = threadIdx.x;
  const int b = blockIdx.y;
  const int L = blockIdx.x * 256 + t;          // 0..36863 (slab-linear)
  const float* src = spart + (size_t)b * 128 * 36864 + L;
  float s0 = 0.f, s1 = 0.f, s2 = 0.f, s3 = 0.f;
  for (int sl = 0; sl < 128; sl += 4) {
    s0 += src[(size_t)sl * 36864];
    s1 += src[(size_t)(sl + 1) * 36864];
    s2 += src[(size_t)(sl + 2) * 36864];
    s3 += src[(size_t)(sl + 3) * 36864];
  }
  const int tsrc = L % 384;
  const int e = L / 384;                       // 0..95
  const int ii = e >> 3, jj = e & 7;
  const int i = (tsrc / 24) * 12 + ii;
  const int j = (tsrc % 24) * 8 + jj;
  S[(size_t)b * 36864 + i * 192 + j] = (s0 + s1) + (s2 + s3);
}

// ---------------------------------------------------------------- K2a
// grid (8, 4): one block per (h, b). From S: T=Wq_h S, U=Wk_h S,
// ssq from T.Wq rows, G = T Wk_h^T, softmax -> A, M = W_out_h @ A.
// Symmetry trick: T[r][j] = sum_i W[r][i]*S[j][i] (row-major S reads).
// nsl: number of spart slices to sum (1 = reduced S, 4 = atomic fallback).
__global__ __launch_bounds__(256) void k2a_softmax_m(
    const float* __restrict__ spart, const float* __restrict__ wqkv,
    const float* __restrict__ temp, const float* __restrict__ wout,
    float* __restrict__ M, const int nsl)
{
  __shared__ float Ws[48][196];   // rows 0..23 = Wq_h, 24..47 = Wk_h
  __shared__ float Ss[192][68];   // Ss[j][il] = S[j][i0+il] (i-chunk of 64)
  __shared__ float Ts[48][196];   // rows 0..23 = T = Wq S, 24..47 = U = Wk S
  __shared__ float Gs[24][24];
  __shared__ float As[24][24];
  __shared__ float ssqs[48];
  __shared__ float rqs[24], rks[24];

  const int t = threadIdx.x;
  const int h = blockIdx.x;
  const int b = blockIdx.y;

  // load Ws: 48 rows x 192 = 2304 f4
#pragma unroll
  for (int u = 0; u < 9; ++u) {
    const int e4 = t + 256 * u;
    const int r = e4 / 48;          // 0..47
    const int c4 = e4 % 48;
    const int gr = (r < 24) ? (h * 24 + r) : (192 + h * 24 + (r - 24));
    *(float4*)&Ws[r][c4 * 4] = *(const float4*)&wqkv[(size_t)gr * 192 + c4 * 4];
  }

  // T/U: thread (rg,jg) owns rows rg+8k (k<6), cols jg+32m (m<6)
  const int rg = t >> 5;            // 0..7
  const int jg = t & 31;            // 0..31
  float tacc[6][6];
#pragma unroll
  for (int k = 0; k < 6; ++k)
#pragma unroll
    for (int m = 0; m < 6; ++m) tacc[k][m] = 0.f;

  for (int ic = 0; ic < 3; ++ic) {
    const int i0 = ic * 64;
    __syncthreads();                 // protect Ss vs previous chunk readers
    // stage Ss[j][il] = S[j][i0+il], summing nsl slices
#pragma unroll
    for (int u = 0; u < 12; ++u) {
      const int e4 = t + 256 * u;
      const int j = e4 >> 4;         // 0..191
      const int il4 = e4 & 15;       // 0..15
      const size_t off = (size_t)j * 192 + i0 + il4 * 4;
      float4 s = make_float4(0.f, 0.f, 0.f, 0.f);
      for (int sl = 0; sl < nsl; ++sl) {
        const float4 v = *(const float4*)&spart[(size_t)(sl * 4 + b) * 36864 + off];
        s.x += v.x; s.y += v.y; s.z += v.z; s.w += v.w;
      }
      *(float4*)&Ss[j][il4 * 4] = s;
    }
    __syncthreads();
#pragma unroll
    for (int il4 = 0; il4 < 16; ++il4) {
      float4 w4[6], s4[6];
#pragma unroll
      for (int k = 0; k < 6; ++k)
        w4[k] = *(const float4*)&Ws[rg + 8 * k][i0 + il4 * 4];
#pragma unroll
      for (int m = 0; m < 6; ++m)
        s4[m] = *(const float4*)&Ss[jg + 32 * m][il4 * 4];
#pragma unroll
      for (int k = 0; k < 6; ++k)
#pragma unroll
        for (int m = 0; m < 6; ++m)
          tacc[k][m] += w4[k].x * s4[m].x + w4[k].y * s4[m].y +
                        w4[k].z * s4[m].z + w4[k].w * s4[m].w;
    }
  }
#pragma unroll
  for (int k = 0; k < 6; ++k)
#pragma unroll
    for (int m = 0; m < 6; ++m)
      Ts[rg + 8 * k][jg + 32 * m] = tacc[k][m];
  __syncthreads();

  // ssq: row r of [T;U] dotted with row r of [Wq;Wk]; 4 threads/row
  if (t < 192) {
    const int r = t >> 2, q = t & 3;
    float s = 0.f;
#pragma unroll
    for (int u = 0; u < 12; ++u) {
      const int j4 = q * 12 + u;
      const float4 tv = *(const float4*)&Ts[r][j4 * 4];
      const float4 wv = *(const float4*)&Ws[r][j4 * 4];
      s += tv.x * wv.x + tv.y * wv.y + tv.z * wv.z + tv.w * wv.w;
    }
    s += __shfl_xor(s, 1);
    s += __shfl_xor(s, 2);
    if (q == 0) ssqs[r] = s;
  }
  // G[c][d] = T[c] . Wk[d]
#pragma unroll
  for (int u = 0; u < 3; ++u) {
    const int idx = t + 256 * u;
    if (idx < 576) {
      const int c = idx / 24, d = idx % 24;
      float s = 0.f;
#pragma unroll
      for (int j4 = 0; j4 < 48; ++j4) {
        const float4 tv = *(const float4*)&Ts[c][j4 * 4];
        const float4 wv = *(const float4*)&Ws[24 + d][j4 * 4];
        s += tv.x * wv.x + tv.y * wv.y + tv.z * wv.z + tv.w * wv.w;
      }
      Gs[c][d] = s;
    }
  }
  __syncthreads();
  if (t < 24) rqs[t] = 1.f / fmaxf(sqrtf(ssqs[t]), L2EPS);
  else if (t >= 32 && t < 56) rks[t - 32] = 1.f / fmaxf(sqrtf(ssqs[24 + t - 32]), L2EPS);
  __syncthreads();

  if (t < 24) {
    const float tempv = temp[h];
    const float rqc = rqs[t];
    float v[24];
    float m = -1e30f;
#pragma unroll
    for (int d = 0; d < 24; ++d) {
      v[d] = Gs[t][d] * tempv * rqc * rks[d];
      m = fmaxf(m, v[d]);
    }
    float s = 0.f;
#pragma unroll
    for (int d = 0; d < 24; ++d) { v[d] = expf(v[d] - m); s += v[d]; }
    const float inv = 1.f / s;
#pragma unroll
    for (int d = 0; d < 24; ++d) As[t][d] = v[d] * inv;
  }
  __syncthreads();

  // M[o][h*24+j] = sum_i wout[o][h*24+i] * As[i][j]; 192*24 = 4608 = 256*18
#pragma unroll
  for (int u = 0; u < 18; ++u) {
    const int p = t + 256 * u;
    const int o = p / 24, j = p % 24;
    float s = 0.f;
#pragma unroll
    for (int i = 0; i < 24; ++i)
      s += wout[o * 192 + h * 24 + i] * As[i][j];
    M[((size_t)b * 192 + o) * 192 + h * 24 + j] = s;
  }
}

// ---------------------------------------------------------------- K2b
// grid (24, 4): P_b = M_b @ Wv  (192x192 @ 192x192), 8 rows per block.
__global__ __launch_bounds__(256) void k2b_p(
    const float* __restrict__ M, const float* __restrict__ wqkv,
    float* __restrict__ P)
{
  __shared__ float Ms[8][192];
  const int t = threadIdx.x;
  const int r0 = blockIdx.x * 8;
  const int b = blockIdx.y;
  for (int e = t; e < 1536; e += 256)
    (&Ms[0][0])[e] = M[((size_t)b * 192 + r0) * 192 + e];
  __syncthreads();
  const float4* wv4 = (const float4*)(wqkv + 384 * 192);
#pragma unroll
  for (int u = 0; u < 2; ++u) {
    const int idx4 = t + 256 * u;
    if (idx4 < 384) {
      const int ol = idx4 / 48, c4 = idx4 % 48;
      float4 a = make_float4(0.f, 0.f, 0.f, 0.f);
      for (int c = 0; c < 192; ++c) {
        const float m = Ms[ol][c];
        const float4 w = wv4[c * 48 + c4];
        a.x += m * w.x; a.y += m * w.y; a.z += m * w.z; a.w += m * w.w;
      }
      ((float4*)P)[((size_t)b * 192 + r0 + ol) * 48 + c4] = a;
    }
  }
}

// ---------------------------------------------------------------- K3
// out_b = P_b @ x_b. grid (512, 4), 256 thr. Block tile 192x128,
// thread tile 12x8 (96 acc), c-chunks of 32 (12 barriers total).
// Ps staged transposed [c][r]; Xs natural [c][n].
__global__ __launch_bounds__(256, 3) void k3_out(
    const float* __restrict__ P, const float* __restrict__ x,
    float* __restrict__ out)
{
  __shared__ float Ps[32][196];
  __shared__ float Xs[32][132];
  const int t = threadIdx.x;
  const int b = blockIdx.y;
  const int n0 = blockIdx.x * 128;
  const int ti = t >> 4;              // 0..15 -> 12-row strip
  const int tj = t & 15;              // 0..15 -> 8-col strip
  const int r0 = ti * 12;
  const float* xb = x + (size_t)b * 192 * 65536;
  const float4* Pb4 = (const float4*)(P + (size_t)b * 36864);

  float acc[12][8];
#pragma unroll
  for (int i = 0; i < 12; ++i)
#pragma unroll
    for (int j = 0; j < 8; ++j) acc[i][j] = 0.f;

  for (int cb = 0; cb < 6; ++cb) {
    // stage Xs: 32 rows x 128 cols = 1024 f4, 4/thread
#pragma unroll
    for (int u = 0; u < 4; ++u) {
      const int e = t + 256 * u;       // 0..1023
      const int cl = e >> 5;           // 0..31
      const int n4 = e & 31;           // 0..31
      *(float4*)&Xs[cl][n4 * 4] =
          *(const float4*)&xb[(size_t)(cb * 32 + cl) * 65536 + n0 + n4 * 4];
    }
    // stage Ps transposed: 192 rows x 8 f4 = 1536 f4, 6/thread
#pragma unroll
    for (int u = 0; u < 6; ++u) {
      const int e4 = t + 256 * u;      // 0..1535
      const int r = e4 >> 3;           // 0..191
      const int q = e4 & 7;            // 0..7
      const float4 w = Pb4[r * 48 + cb * 8 + q];
      Ps[q * 4 + 0][r] = w.x; Ps[q * 4 + 1][r] = w.y;
      Ps[q * 4 + 2][r] = w.z; Ps[q * 4 + 3][r] = w.w;
    }
    __syncthreads();
#pragma unroll 2
    for (int c = 0; c < 32; ++c) {
      const float4 a0 = *(const float4*)&Ps[c][r0];
      const float4 a1 = *(const float4*)&Ps[c][r0 + 4];
      const float4 a2 = *(const float4*)&Ps[c][r0 + 8];
      const float4 c0 = *(const float4*)&Xs[c][tj * 8];
      const float4 c1 = *(const float4*)&Xs[c][tj * 8 + 4];
      ROW8(0, a0.x)  ROW8(1, a0.y)  ROW8(2, a0.z)  ROW8(3, a0.w)
      ROW8(4, a1.x)  ROW8(5, a1.y)  ROW8(6, a1.z)  ROW8(7, a1.w)
      ROW8(8, a2.x)  ROW8(9, a2.y)  ROW8(10, a2.z) ROW8(11, a2.w)
    }
    __syncthreads();
  }
  float* ob = out + ((size_t)b * 192 + r0) * 65536 + n0 + tj * 8;
#pragma unroll
  for (int i = 0; i < 12; ++i) {
    *(float4*)&ob[(size_t)i * 65536] =
        make_float4(acc[i][0], acc[i][1], acc[i][2], acc[i][3]);
    *(float4*)&ob[(size_t)i * 65536 + 4] =
        make_float4(acc[i][4], acc[i][5], acc[i][6], acc[i][7]);
  }
}

// ---------------------------------------------------------------- launch
extern "C" void kernel_launch(void* const* d_in, const int* in_sizes, int n_in,
                              void* d_out, int out_size, void* d_ws, size_t ws_size,
                              hipStream_t stream) {
  const float* x    = (const float*)d_in[0];
  const float* wqkv = (const float*)d_in[1];
  const float* wout = (const float*)d_in[2];
  const float* temp = (const float*)d_in[3];
  float* out = (float*)d_out;
  float* ws  = (float*)d_ws;

  // Exclusive-slab path needs 128 slabs * 4 b * 36864 + S + M + P floats.
  const size_t slabs_fl = (size_t)128 * 4 * 36864;      // 18,874,368
  const size_t need = (slabs_fl + (size_t)3 * 147456) * sizeof(float); // ~77.3MB

  if (ws_size >= need) {
    float* spart = ws;
    float* S = ws + slabs_fl;
    float* M = S + 147456;
    float* P = M + 147456;
    k1s_xxt<<<dim3(128, 4), 384, 0, stream>>>(x, spart, 1);
    kreduce<<<dim3(144, 4), 256, 0, stream>>>(spart, S);
    k2a_softmax_m<<<dim3(8, 4), 256, 0, stream>>>(S, wqkv, temp, wout, M, 1);
    k2b_p<<<dim3(24, 4), 256, 0, stream>>>(M, wqkv, P);
    k3_out<<<dim3(512, 4), 256, 0, stream>>>(P, x, out);
  } else {
    // fallback: round-1 memory plan (4-slice atomic spart)
    float* spart = ws;               // 589824 floats
    float* M = ws + 589824;          // 147456
    float* P = M + 147456;           // 147456
    hipMemsetAsync(d_ws, 0, (size_t)589824 * sizeof(float), stream);
    k1s_xxt<<<dim3(128, 4), 384, 0, stream>>>(x, spart, 0);
    k2a_softmax_m<<<dim3(8, 4), 256, 0, stream>>>(spart, wqkv, temp, wout, M, 4);
    k2b_p<<<dim3(24, 4), 256, 0, stream>>>(M, wqkv, P);
    k3_out<<<dim3(512, 4), 256, 0, stream>>>(P, x, out);
  }
}

// Round 3
// 640.913 us; speedup vs baseline: 2.5381x; 1.3189x over previous
//
#include <hip/hip_runtime.h>
#include <math.h>

// Problem: B=4, C=192, H=W=256 -> N=65536, heads=8, Ch=24
//
// Factorization through S = X X^T (Q,K only consumed via row-reductions):
//   S_b    = X_b X_b^T (192x192)                      [K1 mfma bf16 (+Kred)]
//   T = Wq_h S;  ssq_q[c] = T[c].Wq[c]  (sym. trick)  [K2a]
//   G_h = T Wk_h^T;  attn = softmax(G*temp/(|q||k|))  [K2a]
//   M_b  = W_out * blockdiag(attn)                    [K2a]
//   P_b  = M_b * W_v                                  [K2b]
//   out  = P_b * x_b                                  [K3, fp32]
//
// Round-3:
//  * k1 -> bf16 MFMA (32x32x16). Numerics: bf16 X perturbs logits by
//    ~1.5e-5 (denominator |q||k| ~ 65536) -> invisible. Kernel becomes
//    HBM-bound (201MB read -> ~32us floor) instead of 314us VALU/LDS.
//    Slabs written in natural (i,j) layout via verified C/D mapping.
//  * k3: c-side columns split tj*4 / tj*4+64 (4-way bank conflict -> 2-way
//    free). k3 stays fp32: its bf16 error would land directly on out.
//  * no atomics, no memset anywhere.

#define L2EPS 1e-12f

typedef __attribute__((ext_vector_type(8))) short bf16x8;
typedef __attribute__((ext_vector_type(16))) float f32x16;

__device__ __forceinline__ unsigned bf2pack(float a, float b) {
  unsigned ua = __float_as_uint(a);
  unsigned ub = __float_as_uint(b);
  ua += 0x7FFFu + ((ua >> 16) & 1u);     // round-to-nearest-even
  ub += 0x7FFFu + ((ub >> 16) & 1u);
  return (ua >> 16) | (ub & 0xFFFF0000u);
}

// acc[rr][0..7] += av * {c0,c1}
#define ROW8(rr, av)                                                     \
  acc[rr][0] += (av) * c0.x; acc[rr][1] += (av) * c0.y;                  \
  acc[rr][2] += (av) * c0.z; acc[rr][3] += (av) * c0.w;                  \
  acc[rr][4] += (av) * c1.x; acc[rr][5] += (av) * c1.y;                  \
  acc[rr][6] += (av) * c1.z; acc[rr][7] += (av) * c1.w;

// ---------------------------------------------------------------- K1 (MFMA)
// S_b = X_b X_b^T in bf16 MFMA, fp32 accumulate. grid (128, 4), 256 thr
// (4 waves), 2 blocks/CU. Block: n-chunk of 512, k-tiles of 64.
// LDS: X tile 192x64 bf16, row stride 72 el (144B = 9 quad-banks, gcd(9,8)=1
// -> balanced b128 frag reads). Wave w owns 96x96 quadrant (3x3 32x32 tiles).
// A-frag lane l: row l&31, k (l>>5)*8+e; B = X^T -> identical read at the
// column block's row base. Slab written natural layout via C/D mapping
// col=l&31, row=(g&3)+8*(g>>2)+4*(l>>5).
__global__ __launch_bounds__(256, 2) void k1_mfma(
    const float* __restrict__ x, float* __restrict__ spart)
{
  __shared__ unsigned short Xs[192 * 72];   // bf16, 27.6 KB
  const int t = threadIdx.x;
  const int b = blockIdx.y;
  const int bx = blockIdx.x;                // 0..127 -> n-chunk of 512
  const int lane = t & 63;
  const int w = t >> 6;                     // wave 0..3
  const int wr = (w >> 1) * 96;             // wave row base
  const int wc = (w & 1) * 96;              // wave col base
  const int l31 = lane & 31;
  const int lk = (lane >> 5) * 8;           // k sub-offset (elements)

  f32x16 acc[3][3];
#pragma unroll
  for (int i = 0; i < 3; ++i)
#pragma unroll
    for (int j = 0; j < 3; ++j)
#pragma unroll
      for (int g = 0; g < 16; ++g) acc[i][j][g] = 0.f;

  const float* xb = x + (size_t)b * 192 * 65536;

  for (int kt = 0; kt < 8; ++kt) {
    const int n0 = bx * 512 + kt * 64;
    // issue global loads first (overlap with other waves' tail compute)
    float4 ld[12];
#pragma unroll
    for (int u = 0; u < 12; ++u) {
      const int e = t + 256 * u;            // 0..3071
      const int r = e >> 4, k4 = e & 15;
      ld[u] = *(const float4*)&xb[(size_t)r * 65536 + n0 + k4 * 4];
    }
    __syncthreads();                        // previous tile's readers done
#pragma unroll
    for (int u = 0; u < 12; ++u) {
      const int e = t + 256 * u;
      const int r = e >> 4, k4 = e & 15;
      const unsigned lo = bf2pack(ld[u].x, ld[u].y);
      const unsigned hi = bf2pack(ld[u].z, ld[u].w);
      *(uint2*)&Xs[r * 72 + k4 * 4] = make_uint2(lo, hi);
    }
    __syncthreads();
#pragma unroll
    for (int ks = 0; ks < 4; ++ks) {        // 4 k-slices of 16
      bf16x8 af[3], bf[3];
#pragma unroll
      for (int i = 0; i < 3; ++i) {
        af[i] = *(const bf16x8*)&Xs[(wr + i * 32 + l31) * 72 + ks * 16 + lk];
        bf[i] = *(const bf16x8*)&Xs[(wc + i * 32 + l31) * 72 + ks * 16 + lk];
      }
#pragma unroll
      for (int i = 0; i < 3; ++i)
#pragma unroll
        for (int j = 0; j < 3; ++j)
          acc[i][j] = __builtin_amdgcn_mfma_f32_32x32x16_bf16(
              af[i], bf[j], acc[i][j], 0, 0, 0);
    }
  }

  // flush to exclusive slab, natural (i,j) layout
  float* sd = spart + (size_t)(b * 128 + bx) * 36864;
#pragma unroll
  for (int i = 0; i < 3; ++i)
#pragma unroll
    for (int j = 0; j < 3; ++j)
#pragma unroll
      for (int g = 0; g < 16; ++g) {
        const int row = wr + i * 32 + (g & 3) + 8 * (g >> 2) + 4 * (lane >> 5);
        const int col = wc + j * 32 + l31;
        sd[row * 192 + col] = acc[i][j][g];
      }
}

// ---------------------------------------------------------------- Kred
// Reduce 128 natural-layout slabs -> S[b][192][192]. grid (144, 4), 256 thr.
__global__ __launch_bounds__(256) void kreduce(
    const float* __restrict__ spart, float* __restrict__ S)
{
  const int t = threadIdx.x;
  const int b = blockIdx.y;
  const int L = blockIdx.x * 256 + t;          // 0..36863
  const float* src = spart + (size_t)b * 128 * 36864 + L;
  float s0 = 0.f, s1 = 0.f, s2 = 0.f, s3 = 0.f;
  for (int sl = 0; sl < 128; sl += 4) {
    s0 += src[(size_t)sl * 36864];
    s1 += src[(size_t)(sl + 1) * 36864];
    s2 += src[(size_t)(sl + 2) * 36864];
    s3 += src[(size_t)(sl + 3) * 36864];
  }
  S[(size_t)b * 36864 + L] = (s0 + s1) + (s2 + s3);
}

// ---------------------------------------------------------------- K2a
// grid (8, 4): one block per (h, b). From S: T=Wq_h S, U=Wk_h S,
// ssq from T.Wq rows, G = T Wk_h^T, softmax -> A, M = W_out_h @ A.
// Symmetry trick: T[r][j] = sum_i W[r][i]*S[j][i] (row-major S reads).
__global__ __launch_bounds__(256) void k2a_softmax_m(
    const float* __restrict__ spart, const float* __restrict__ wqkv,
    const float* __restrict__ temp, const float* __restrict__ wout,
    float* __restrict__ M, const int nsl)
{
  __shared__ float Ws[48][196];   // rows 0..23 = Wq_h, 24..47 = Wk_h
  __shared__ float Ss[192][68];   // Ss[j][il] = S[j][i0+il] (i-chunk of 64)
  __shared__ float Ts[48][196];   // rows 0..23 = T = Wq S, 24..47 = U = Wk S
  __shared__ float Gs[24][24];
  __shared__ float As[24][24];
  __shared__ float ssqs[48];
  __shared__ float rqs[24], rks[24];

  const int t = threadIdx.x;
  const int h = blockIdx.x;
  const int b = blockIdx.y;

  // load Ws: 48 rows x 192 = 2304 f4
#pragma unroll
  for (int u = 0; u < 9; ++u) {
    const int e4 = t + 256 * u;
    const int r = e4 / 48;          // 0..47
    const int c4 = e4 % 48;
    const int gr = (r < 24) ? (h * 24 + r) : (192 + h * 24 + (r - 24));
    *(float4*)&Ws[r][c4 * 4] = *(const float4*)&wqkv[(size_t)gr * 192 + c4 * 4];
  }

  // T/U: thread (rg,jg) owns rows rg+8k (k<6), cols jg+32m (m<6)
  const int rg = t >> 5;            // 0..7
  const int jg = t & 31;            // 0..31
  float tacc[6][6];
#pragma unroll
  for (int k = 0; k < 6; ++k)
#pragma unroll
    for (int m = 0; m < 6; ++m) tacc[k][m] = 0.f;

  for (int ic = 0; ic < 3; ++ic) {
    const int i0 = ic * 64;
    __syncthreads();                 // protect Ss vs previous chunk readers
    // stage Ss[j][il] = S[j][i0+il], summing nsl slices
#pragma unroll
    for (int u = 0; u < 12; ++u) {
      const int e4 = t + 256 * u;
      const int j = e4 >> 4;         // 0..191
      const int il4 = e4 & 15;       // 0..15
      const size_t off = (size_t)j * 192 + i0 + il4 * 4;
      float4 s = make_float4(0.f, 0.f, 0.f, 0.f);
      for (int sl = 0; sl < nsl; ++sl) {
        const float4 v = *(const float4*)&spart[(size_t)(sl * 4 + b) * 36864 + off];
        s.x += v.x; s.y += v.y; s.z += v.z; s.w += v.w;
      }
      *(float4*)&Ss[j][il4 * 4] = s;
    }
    __syncthreads();
#pragma unroll
    for (int il4 = 0; il4 < 16; ++il4) {
      float4 w4[6], s4[6];
#pragma unroll
      for (int k = 0; k < 6; ++k)
        w4[k] = *(const float4*)&Ws[rg + 8 * k][i0 + il4 * 4];
#pragma unroll
      for (int m = 0; m < 6; ++m)
        s4[m] = *(const float4*)&Ss[jg + 32 * m][il4 * 4];
#pragma unroll
      for (int k = 0; k < 6; ++k)
#pragma unroll
        for (int m = 0; m < 6; ++m)
          tacc[k][m] += w4[k].x * s4[m].x + w4[k].y * s4[m].y +
                        w4[k].z * s4[m].z + w4[k].w * s4[m].w;
    }
  }
#pragma unroll
  for (int k = 0; k < 6; ++k)
#pragma unroll
    for (int m = 0; m < 6; ++m)
      Ts[rg + 8 * k][jg + 32 * m] = tacc[k][m];
  __syncthreads();

  // ssq: row r of [T;U] dotted with row r of [Wq;Wk]; 4 threads/row
  if (t < 192) {
    const int r = t >> 2, q = t & 3;
    float s = 0.f;
#pragma unroll
    for (int u = 0; u < 12; ++u) {
      const int j4 = q * 12 + u;
      const float4 tv = *(const float4*)&Ts[r][j4 * 4];
      const float4 wv = *(const float4*)&Ws[r][j4 * 4];
      s += tv.x * wv.x + tv.y * wv.y + tv.z * wv.z + tv.w * wv.w;
    }
    s += __shfl_xor(s, 1);
    s += __shfl_xor(s, 2);
    if (q == 0) ssqs[r] = s;
  }
  // G[c][d] = T[c] . Wk[d]
#pragma unroll
  for (int u = 0; u < 3; ++u) {
    const int idx = t + 256 * u;
    if (idx < 576) {
      const int c = idx / 24, d = idx % 24;
      float s = 0.f;
#pragma unroll
      for (int j4 = 0; j4 < 48; ++j4) {
        const float4 tv = *(const float4*)&Ts[c][j4 * 4];
        const float4 wv = *(const float4*)&Ws[24 + d][j4 * 4];
        s += tv.x * wv.x + tv.y * wv.y + tv.z * wv.z + tv.w * wv.w;
      }
      Gs[c][d] = s;
    }
  }
  __syncthreads();
  if (t < 24) rqs[t] = 1.f / fmaxf(sqrtf(ssqs[t]), L2EPS);
  else if (t >= 32 && t < 56) rks[t - 32] = 1.f / fmaxf(sqrtf(ssqs[24 + t - 32]), L2EPS);
  __syncthreads();

  if (t < 24) {
    const float tempv = temp[h];
    const float rqc = rqs[t];
    float v[24];
    float m = -1e30f;
#pragma unroll
    for (int d = 0; d < 24; ++d) {
      v[d] = Gs[t][d] * tempv * rqc * rks[d];
      m = fmaxf(m, v[d]);
    }
    float s = 0.f;
#pragma unroll
    for (int d = 0; d < 24; ++d) { v[d] = expf(v[d] - m); s += v[d]; }
    const float inv = 1.f / s;
#pragma unroll
    for (int d = 0; d < 24; ++d) As[t][d] = v[d] * inv;
  }
  __syncthreads();

  // M[o][h*24+j] = sum_i wout[o][h*24+i] * As[i][j]; 192*24 = 4608 = 256*18
#pragma unroll
  for (int u = 0; u < 18; ++u) {
    const int p = t + 256 * u;
    const int o = p / 24, j = p % 24;
    float s = 0.f;
#pragma unroll
    for (int i = 0; i < 24; ++i)
      s += wout[o * 192 + h * 24 + i] * As[i][j];
    M[((size_t)b * 192 + o) * 192 + h * 24 + j] = s;
  }
}

// ---------------------------------------------------------------- K2b
// grid (24, 4): P_b = M_b @ Wv  (192x192 @ 192x192), 8 rows per block.
__global__ __launch_bounds__(256) void k2b_p(
    const float* __restrict__ M, const float* __restrict__ wqkv,
    float* __restrict__ P)
{
  __shared__ float Ms[8][192];
  const int t = threadIdx.x;
  const int r0 = blockIdx.x * 8;
  const int b = blockIdx.y;
  for (int e = t; e < 1536; e += 256)
    (&Ms[0][0])[e] = M[((size_t)b * 192 + r0) * 192 + e];
  __syncthreads();
  const float4* wv4 = (const float4*)(wqkv + 384 * 192);
#pragma unroll
  for (int u = 0; u < 2; ++u) {
    const int idx4 = t + 256 * u;
    if (idx4 < 384) {
      const int ol = idx4 / 48, c4 = idx4 % 48;
      float4 a = make_float4(0.f, 0.f, 0.f, 0.f);
      for (int c = 0; c < 192; ++c) {
        const float m = Ms[ol][c];
        const float4 w = wv4[c * 48 + c4];
        a.x += m * w.x; a.y += m * w.y; a.z += m * w.z; a.w += m * w.w;
      }
      ((float4*)P)[((size_t)b * 192 + r0 + ol) * 48 + c4] = a;
    }
  }
}

// ---------------------------------------------------------------- K3
// out_b = P_b @ x_b. grid (512, 4), 256 thr. Block tile 192x128,
// thread tile 12x8 (96 acc), c-chunks of 32.
// Thread's 8 cols split as {tj*4..+3} U {tj*4+64..+67}: c-side LDS read
// goes 4-way -> 2-way (free); out writes stay 256B-coalesced.
__global__ __launch_bounds__(256, 3) void k3_out(
    const float* __restrict__ P, const float* __restrict__ x,
    float* __restrict__ out)
{
  __shared__ float Ps[32][196];
  __shared__ float Xs[32][132];
  const int t = threadIdx.x;
  const int b = blockIdx.y;
  const int n0 = blockIdx.x * 128;
  const int ti = t >> 4;              // 0..15 -> 12-row strip
  const int tj = t & 15;              // 0..15 -> two 4-col strips
  const int r0 = ti * 12;
  const float* xb = x + (size_t)b * 192 * 65536;
  const float4* Pb4 = (const float4*)(P + (size_t)b * 36864);

  float acc[12][8];
#pragma unroll
  for (int i = 0; i < 12; ++i)
#pragma unroll
    for (int j = 0; j < 8; ++j) acc[i][j] = 0.f;

  for (int cb = 0; cb < 6; ++cb) {
    // stage Xs: 32 rows x 128 cols = 1024 f4, 4/thread
#pragma unroll
    for (int u = 0; u < 4; ++u) {
      const int e = t + 256 * u;       // 0..1023
      const int cl = e >> 5;           // 0..31
      const int n4 = e & 31;           // 0..31
      *(float4*)&Xs[cl][n4 * 4] =
          *(const float4*)&xb[(size_t)(cb * 32 + cl) * 65536 + n0 + n4 * 4];
    }
    // stage Ps transposed: 192 rows x 8 f4 = 1536 f4, 6/thread
#pragma unroll
    for (int u = 0; u < 6; ++u) {
      const int e4 = t + 256 * u;      // 0..1535
      const int r = e4 >> 3;           // 0..191
      const int q = e4 & 7;            // 0..7
      const float4 w = Pb4[r * 48 + cb * 8 + q];
      Ps[q * 4 + 0][r] = w.x; Ps[q * 4 + 1][r] = w.y;
      Ps[q * 4 + 2][r] = w.z; Ps[q * 4 + 3][r] = w.w;
    }
    __syncthreads();
#pragma unroll 2
    for (int c = 0; c < 32; ++c) {
      const float4 a0 = *(const float4*)&Ps[c][r0];
      const float4 a1 = *(const float4*)&Ps[c][r0 + 4];
      const float4 a2 = *(const float4*)&Ps[c][r0 + 8];
      const float4 c0 = *(const float4*)&Xs[c][tj * 4];
      const float4 c1 = *(const float4*)&Xs[c][tj * 4 + 64];
      ROW8(0, a0.x)  ROW8(1, a0.y)  ROW8(2, a0.z)  ROW8(3, a0.w)
      ROW8(4, a1.x)  ROW8(5, a1.y)  ROW8(6, a1.z)  ROW8(7, a1.w)
      ROW8(8, a2.x)  ROW8(9, a2.y)  ROW8(10, a2.z) ROW8(11, a2.w)
    }
    __syncthreads();
  }
  float* ob = out + ((size_t)b * 192 + r0) * 65536 + n0;
#pragma unroll
  for (int i = 0; i < 12; ++i) {
    *(float4*)&ob[(size_t)i * 65536 + tj * 4] =
        make_float4(acc[i][0], acc[i][1], acc[i][2], acc[i][3]);
    *(float4*)&ob[(size_t)i * 65536 + tj * 4 + 64] =
        make_float4(acc[i][4], acc[i][5], acc[i][6], acc[i][7]);
  }
}

// ---------------------------------------------------------------- launch
extern "C" void kernel_launch(void* const* d_in, const int* in_sizes, int n_in,
                              void* d_out, int out_size, void* d_ws, size_t ws_size,
                              hipStream_t stream) {
  const float* x    = (const float*)d_in[0];
  const float* wqkv = (const float*)d_in[1];
  const float* wout = (const float*)d_in[2];
  const float* temp = (const float*)d_in[3];
  float* out = (float*)d_out;
  float* ws  = (float*)d_ws;

  // slabs: 128 per batch * 4 b * 36864 floats (proven to fit in round 2)
  const size_t slabs_fl = (size_t)128 * 4 * 36864;      // 18,874,368
  float* spart = ws;
  float* S = ws + slabs_fl;        // 147456 floats
  float* M = S + 147456;           // 147456
  float* P = M + 147456;           // 147456

  k1_mfma<<<dim3(128, 4), 256, 0, stream>>>(x, spart);
  kreduce<<<dim3(144, 4), 256, 0, stream>>>(spart, S);
  k2a_softmax_m<<<dim3(8, 4), 256, 0, stream>>>(S, wqkv, temp, wout, M, 1);
  k2b_p<<<dim3(24, 4), 256, 0, stream>>>(M, wqkv, P);
  k3_out<<<dim3(512, 4), 256, 0, stream>>>(P, x, out);
}

// Round 4
// 639.774 us; speedup vs baseline: 2.5426x; 1.0018x over previous
//
#include <hip/hip_runtime.h>
#include <math.h>

// Problem: B=4, C=192, H=W=256 -> N=65536, heads=8, Ch=24
//
// Factorization through S = X X^T (Q,K only consumed via row-reductions):
//   S_b    = X_b X_b^T (192x192)                      [K1 mfma bf16 (+Kred)]
//   T = Wq_h S;  ssq_q[c] = T[c].Wq[c]  (sym. trick)  [K2a]
//   G_h = T Wk_h^T;  attn = softmax(G*temp/(|q||k|))  [K2a]
//   M_b  = W_out * blockdiag(attn)                    [K2a]
//   P_b  = M_b * W_v  -> split bf16 Phi+Plo           [K2b]
//   out  = Phi@xhi + Phi@xlo + Plo@xhi  (MFMA)        [K3 mfma]
//
// Round-4:
//  * k1: no LDS, no barriers. Reduction dim n is CONTIGUOUS in x, so MFMA
//    fragments load directly from global (x is L3-resident) + in-reg bf16
//    pack. Round-3 k1 serialized on the vmcnt(0) drain at every barrier.
//  * k3 -> split-bf16 MFMA (error ~2^-18 ~= fp32; Sterbenz-exact residual).
//    Replaces the fp32 VALU GEMM that was pinned at its 123us issue floor.
//  * k2b emits Phi/Plo bf16 instead of fp32 P.

#define L2EPS 1e-12f

typedef __attribute__((ext_vector_type(8))) short bf16x8;
typedef __attribute__((ext_vector_type(16))) float f32x16;
typedef union { bf16x8 v; unsigned u[4]; } packer;

__device__ __forceinline__ unsigned bf2pack(float a, float b) {
  unsigned ua = __float_as_uint(a);
  unsigned ub = __float_as_uint(b);
  ua += 0x7FFFu + ((ua >> 16) & 1u);     // round-to-nearest-even
  ub += 0x7FFFu + ((ub >> 16) & 1u);
  return (ua >> 16) | (ub & 0xFFFF0000u);
}
__device__ __forceinline__ unsigned short bfh(float v) {
  unsigned u = __float_as_uint(v);
  u += 0x7FFFu + ((u >> 16) & 1u);
  return (unsigned short)(u >> 16);
}
__device__ __forceinline__ float hf(unsigned short h) {
  return __uint_as_float((unsigned)h << 16);
}

// ---------------------------------------------------------------- K1 (MFMA)
// S_b = X_b X_b^T, bf16 MFMA 32x32x16, fp32 acc. grid (128, 4), 256 thr
// (4 waves, each owns a 96x96 quadrant = 3x3 tiles). No LDS, no barriers:
// each lane loads its 8-consecutive-n fragment straight from global
// (x L3-resident; per-block 16-n window 12KB ~ L1) and packs to bf16.
// Slab written natural (i,j) layout via verified C/D mapping.
__global__ __launch_bounds__(256, 2) void k1_mfma(
    const float* __restrict__ x, float* __restrict__ spart)
{
  const int t = threadIdx.x;
  const int b = blockIdx.y;
  const int bx = blockIdx.x;                // n-window of 512
  const int lane = t & 63;
  const int w = t >> 6;
  const int wr = (w >> 1) * 96;
  const int wc = (w & 1) * 96;
  const int l31 = lane & 31;
  const int lk = (lane >> 5) * 8;

  f32x16 acc[3][3];
#pragma unroll
  for (int i = 0; i < 3; ++i)
#pragma unroll
    for (int j = 0; j < 3; ++j)
#pragma unroll
      for (int g = 0; g < 16; ++g) acc[i][j][g] = 0.f;

  const float* xb = x + (size_t)b * 192 * 65536;
  const float* ar = xb + (size_t)(wr + l31) * 65536 + lk;
  const float* br = xb + (size_t)(wc + l31) * 65536 + lk;

  for (int ns = 0; ns < 32; ++ns) {
    const int n0 = bx * 512 + ns * 16;
    bf16x8 af[3], bfg[3];
#pragma unroll
    for (int i = 0; i < 3; ++i) {
      const float4 a0 = *(const float4*)(ar + (size_t)(i * 32) * 65536 + n0);
      const float4 a1 = *(const float4*)(ar + (size_t)(i * 32) * 65536 + n0 + 4);
      packer pa;
      pa.u[0] = bf2pack(a0.x, a0.y); pa.u[1] = bf2pack(a0.z, a0.w);
      pa.u[2] = bf2pack(a1.x, a1.y); pa.u[3] = bf2pack(a1.z, a1.w);
      af[i] = pa.v;
      const float4 b0 = *(const float4*)(br + (size_t)(i * 32) * 65536 + n0);
      const float4 b1 = *(const float4*)(br + (size_t)(i * 32) * 65536 + n0 + 4);
      packer pb;
      pb.u[0] = bf2pack(b0.x, b0.y); pb.u[1] = bf2pack(b0.z, b0.w);
      pb.u[2] = bf2pack(b1.x, b1.y); pb.u[3] = bf2pack(b1.z, b1.w);
      bfg[i] = pb.v;
    }
#pragma unroll
    for (int i = 0; i < 3; ++i)
#pragma unroll
      for (int j = 0; j < 3; ++j)
        acc[i][j] = __builtin_amdgcn_mfma_f32_32x32x16_bf16(
            af[i], bfg[j], acc[i][j], 0, 0, 0);
  }

  float* sd = spart + (size_t)(b * 128 + bx) * 36864;
#pragma unroll
  for (int i = 0; i < 3; ++i)
#pragma unroll
    for (int j = 0; j < 3; ++j)
#pragma unroll
      for (int g = 0; g < 16; ++g) {
        const int row = wr + i * 32 + (g & 3) + 8 * (g >> 2) + 4 * (lane >> 5);
        const int col = wc + j * 32 + l31;
        sd[row * 192 + col] = acc[i][j][g];
      }
}

// ---------------------------------------------------------------- Kred
// Reduce 128 natural-layout slabs -> S[b][192][192]. grid (144, 4), 256 thr.
__global__ __launch_bounds__(256) void kreduce(
    const float* __restrict__ spart, float* __restrict__ S)
{
  const int t = threadIdx.x;
  const int b = blockIdx.y;
  const int L = blockIdx.x * 256 + t;          // 0..36863
  const float* src = spart + (size_t)b * 128 * 36864 + L;
  float s0 = 0.f, s1 = 0.f, s2 = 0.f, s3 = 0.f;
  for (int sl = 0; sl < 128; sl += 4) {
    s0 += src[(size_t)sl * 36864];
    s1 += src[(size_t)(sl + 1) * 36864];
    s2 += src[(size_t)(sl + 2) * 36864];
    s3 += src[(size_t)(sl + 3) * 36864];
  }
  S[(size_t)b * 36864 + L] = (s0 + s1) + (s2 + s3);
}

// ---------------------------------------------------------------- K2a
// grid (8, 4): one block per (h, b). From S: T=Wq_h S, U=Wk_h S,
// ssq from T.Wq rows, G = T Wk_h^T, softmax -> A, M = W_out_h @ A.
// Symmetry trick: T[r][j] = sum_i W[r][i]*S[j][i] (row-major S reads).
__global__ __launch_bounds__(256) void k2a_softmax_m(
    const float* __restrict__ spart, const float* __restrict__ wqkv,
    const float* __restrict__ temp, const float* __restrict__ wout,
    float* __restrict__ M, const int nsl)
{
  __shared__ float Ws[48][196];   // rows 0..23 = Wq_h, 24..47 = Wk_h
  __shared__ float Ss[192][68];   // Ss[j][il] = S[j][i0+il] (i-chunk of 64)
  __shared__ float Ts[48][196];   // rows 0..23 = T = Wq S, 24..47 = U = Wk S
  __shared__ float Gs[24][24];
  __shared__ float As[24][24];
  __shared__ float ssqs[48];
  __shared__ float rqs[24], rks[24];

  const int t = threadIdx.x;
  const int h = blockIdx.x;
  const int b = blockIdx.y;

  // load Ws: 48 rows x 192 = 2304 f4
#pragma unroll
  for (int u = 0; u < 9; ++u) {
    const int e4 = t + 256 * u;
    const int r = e4 / 48;          // 0..47
    const int c4 = e4 % 48;
    const int gr = (r < 24) ? (h * 24 + r) : (192 + h * 24 + (r - 24));
    *(float4*)&Ws[r][c4 * 4] = *(const float4*)&wqkv[(size_t)gr * 192 + c4 * 4];
  }

  // T/U: thread (rg,jg) owns rows rg+8k (k<6), cols jg+32m (m<6)
  const int rg = t >> 5;            // 0..7
  const int jg = t & 31;            // 0..31
  float tacc[6][6];
#pragma unroll
  for (int k = 0; k < 6; ++k)
#pragma unroll
    for (int m = 0; m < 6; ++m) tacc[k][m] = 0.f;

  for (int ic = 0; ic < 3; ++ic) {
    const int i0 = ic * 64;
    __syncthreads();                 // protect Ss vs previous chunk readers
    // stage Ss[j][il] = S[j][i0+il], summing nsl slices
#pragma unroll
    for (int u = 0; u < 12; ++u) {
      const int e4 = t + 256 * u;
      const int j = e4 >> 4;         // 0..191
      const int il4 = e4 & 15;       // 0..15
      const size_t off = (size_t)j * 192 + i0 + il4 * 4;
      float4 s = make_float4(0.f, 0.f, 0.f, 0.f);
      for (int sl = 0; sl < nsl; ++sl) {
        const float4 v = *(const float4*)&spart[(size_t)(sl * 4 + b) * 36864 + off];
        s.x += v.x; s.y += v.y; s.z += v.z; s.w += v.w;
      }
      *(float4*)&Ss[j][il4 * 4] = s;
    }
    __syncthreads();
#pragma unroll
    for (int il4 = 0; il4 < 16; ++il4) {
      float4 w4[6], s4[6];
#pragma unroll
      for (int k = 0; k < 6; ++k)
        w4[k] = *(const float4*)&Ws[rg + 8 * k][i0 + il4 * 4];
#pragma unroll
      for (int m = 0; m < 6; ++m)
        s4[m] = *(const float4*)&Ss[jg + 32 * m][il4 * 4];
#pragma unroll
      for (int k = 0; k < 6; ++k)
#pragma unroll
        for (int m = 0; m < 6; ++m)
          tacc[k][m] += w4[k].x * s4[m].x + w4[k].y * s4[m].y +
                        w4[k].z * s4[m].z + w4[k].w * s4[m].w;
    }
  }
#pragma unroll
  for (int k = 0; k < 6; ++k)
#pragma unroll
    for (int m = 0; m < 6; ++m)
      Ts[rg + 8 * k][jg + 32 * m] = tacc[k][m];
  __syncthreads();

  // ssq: row r of [T;U] dotted with row r of [Wq;Wk]; 4 threads/row
  if (t < 192) {
    const int r = t >> 2, q = t & 3;
    float s = 0.f;
#pragma unroll
    for (int u = 0; u < 12; ++u) {
      const int j4 = q * 12 + u;
      const float4 tv = *(const float4*)&Ts[r][j4 * 4];
      const float4 wv = *(const float4*)&Ws[r][j4 * 4];
      s += tv.x * wv.x + tv.y * wv.y + tv.z * wv.z + tv.w * wv.w;
    }
    s += __shfl_xor(s, 1);
    s += __shfl_xor(s, 2);
    if (q == 0) ssqs[r] = s;
  }
  // G[c][d] = T[c] . Wk[d]
#pragma unroll
  for (int u = 0; u < 3; ++u) {
    const int idx = t + 256 * u;
    if (idx < 576) {
      const int c = idx / 24, d = idx % 24;
      float s = 0.f;
#pragma unroll
      for (int j4 = 0; j4 < 48; ++j4) {
        const float4 tv = *(const float4*)&Ts[c][j4 * 4];
        const float4 wv = *(const float4*)&Ws[24 + d][j4 * 4];
        s += tv.x * wv.x + tv.y * wv.y + tv.z * wv.z + tv.w * wv.w;
      }
      Gs[c][d] = s;
    }
  }
  __syncthreads();
  if (t < 24) rqs[t] = 1.f / fmaxf(sqrtf(ssqs[t]), L2EPS);
  else if (t >= 32 && t < 56) rks[t - 32] = 1.f / fmaxf(sqrtf(ssqs[24 + t - 32]), L2EPS);
  __syncthreads();

  if (t < 24) {
    const float tempv = temp[h];
    const float rqc = rqs[t];
    float v[24];
    float m = -1e30f;
#pragma unroll
    for (int d = 0; d < 24; ++d) {
      v[d] = Gs[t][d] * tempv * rqc * rks[d];
      m = fmaxf(m, v[d]);
    }
    float s = 0.f;
#pragma unroll
    for (int d = 0; d < 24; ++d) { v[d] = expf(v[d] - m); s += v[d]; }
    const float inv = 1.f / s;
#pragma unroll
    for (int d = 0; d < 24; ++d) As[t][d] = v[d] * inv;
  }
  __syncthreads();

  // M[o][h*24+j] = sum_i wout[o][h*24+i] * As[i][j]; 192*24 = 4608 = 256*18
#pragma unroll
  for (int u = 0; u < 18; ++u) {
    const int p = t + 256 * u;
    const int o = p / 24, j = p % 24;
    float s = 0.f;
#pragma unroll
    for (int i = 0; i < 24; ++i)
      s += wout[o * 192 + h * 24 + i] * As[i][j];
    M[((size_t)b * 192 + o) * 192 + h * 24 + j] = s;
  }
}

// ---------------------------------------------------------------- K2b
// grid (24, 4): P_b = M_b @ Wv (192x192 @ 192x192), 8 rows per block.
// Emits P as split bf16: Phi = bf16(P), Plo = bf16(P - Phi).
__global__ __launch_bounds__(256) void k2b_p(
    const float* __restrict__ M, const float* __restrict__ wqkv,
    unsigned short* __restrict__ Phi, unsigned short* __restrict__ Plo)
{
  __shared__ float Ms[8][192];
  const int t = threadIdx.x;
  const int r0 = blockIdx.x * 8;
  const int b = blockIdx.y;
  for (int e = t; e < 1536; e += 256)
    (&Ms[0][0])[e] = M[((size_t)b * 192 + r0) * 192 + e];
  __syncthreads();
  const float4* wv4 = (const float4*)(wqkv + 384 * 192);
#pragma unroll
  for (int u = 0; u < 2; ++u) {
    const int idx4 = t + 256 * u;
    if (idx4 < 384) {
      const int ol = idx4 / 48, c4 = idx4 % 48;
      float4 a = make_float4(0.f, 0.f, 0.f, 0.f);
      for (int c = 0; c < 192; ++c) {
        const float m = Ms[ol][c];
        const float4 w = wv4[c * 48 + c4];
        a.x += m * w.x; a.y += m * w.y; a.z += m * w.z; a.w += m * w.w;
      }
      const unsigned short h0 = bfh(a.x), h1 = bfh(a.y);
      const unsigned short h2 = bfh(a.z), h3 = bfh(a.w);
      const unsigned short g0 = bfh(a.x - hf(h0)), g1 = bfh(a.y - hf(h1));
      const unsigned short g2 = bfh(a.z - hf(h2)), g3 = bfh(a.w - hf(h3));
      const size_t o = ((size_t)b * 192 + r0 + ol) * 192 + c4 * 4;
      *(uint2*)&Phi[o] = make_uint2((unsigned)h0 | ((unsigned)h1 << 16),
                                    (unsigned)h2 | ((unsigned)h3 << 16));
      *(uint2*)&Plo[o] = make_uint2((unsigned)g0 | ((unsigned)g1 << 16),
                                    (unsigned)g2 | ((unsigned)g3 << 16));
    }
  }
}

// ---------------------------------------------------------------- K3 (MFMA)
// out_b = P_b @ x_b via split bf16: Phi@xhi + Phi@xlo + Plo@xhi.
// grid (512, 4), 512 thr (8 waves: 2 M-bands x 4 N-subtiles; wave owns
// 96x32 = 3 tiles of 32x32). K-chunks of 32. x chunk staged transposed
// [n][k] in LDS (stride 40 shorts: b64 writes and b128 frag reads both
// bank-floor, 16B-aligned). P frags load direct from global (L1/L2-hot).
__global__ __launch_bounds__(512, 4) void k3_mfma(
    const unsigned short* __restrict__ Phi, const unsigned short* __restrict__ Plo,
    const float* __restrict__ x, float* __restrict__ out)
{
  __shared__ unsigned short Xhi[128 * 40];
  __shared__ unsigned short Xlo[128 * 40];
  const int t = threadIdx.x;
  const int b = blockIdx.y;
  const int n0 = blockIdx.x * 128;
  const int lane = t & 63;
  const int w = t >> 6;               // 0..7
  const int wr = (w >> 2) * 96;       // 0 or 96
  const int wc32 = (w & 3) * 32;
  const int l31 = lane & 31;
  const int lk = (lane >> 5) * 8;

  // staging map (t<256): 4k x 4n patch per thread
  const int nq = ((t >> 6) << 3) | (t & 7);   // 0..31
  const int kq = (t >> 3) & 7;                // 0..7

  const float* xb = x + (size_t)b * 192 * 65536;
  const unsigned short* ph = Phi + (size_t)b * 36864;
  const unsigned short* pl = Plo + (size_t)b * 36864;

  f32x16 acc[3];
#pragma unroll
  for (int i = 0; i < 3; ++i)
#pragma unroll
    for (int g = 0; g < 16; ++g) acc[i][g] = 0.f;

  for (int kc = 0; kc < 6; ++kc) {
    if (t < 256) {
      float4 v[4];
      const float* src = &xb[(size_t)(kc * 32 + kq * 4) * 65536 + n0 + nq * 4];
#pragma unroll
      for (int r = 0; r < 4; ++r) v[r] = *(const float4*)(src + (size_t)r * 65536);
      const float* vf = (const float*)v;      // vf[r*4 + c]
#pragma unroll
      for (int c = 0; c < 4; ++c) {
        const unsigned short h0 = bfh(vf[c]),      h1 = bfh(vf[4 + c]);
        const unsigned short h2 = bfh(vf[8 + c]),  h3 = bfh(vf[12 + c]);
        const unsigned short g0 = bfh(vf[c]      - hf(h0));
        const unsigned short g1 = bfh(vf[4 + c]  - hf(h1));
        const unsigned short g2 = bfh(vf[8 + c]  - hf(h2));
        const unsigned short g3 = bfh(vf[12 + c] - hf(h3));
        const int o = (nq * 4 + c) * 40 + kq * 4;
        *(uint2*)&Xhi[o] = make_uint2((unsigned)h0 | ((unsigned)h1 << 16),
                                      (unsigned)h2 | ((unsigned)h3 << 16));
        *(uint2*)&Xlo[o] = make_uint2((unsigned)g0 | ((unsigned)g1 << 16),
                                      (unsigned)g2 | ((unsigned)g3 << 16));
      }
    }
    __syncthreads();
#pragma unroll
    for (int ks = 0; ks < 2; ++ks) {
      const int kgl = kc * 32 + ks * 16 + lk;
      const bf16x8 bh = *(const bf16x8*)&Xhi[(wc32 + l31) * 40 + ks * 16 + lk];
      const bf16x8 bl = *(const bf16x8*)&Xlo[(wc32 + l31) * 40 + ks * 16 + lk];
#pragma unroll
      for (int i = 0; i < 3; ++i) {
        const bf16x8 ah = *(const bf16x8*)&ph[(size_t)(wr + i * 32 + l31) * 192 + kgl];
        const bf16x8 al = *(const bf16x8*)&pl[(size_t)(wr + i * 32 + l31) * 192 + kgl];
        acc[i] = __builtin_amdgcn_mfma_f32_32x32x16_bf16(ah, bh, acc[i], 0, 0, 0);
        acc[i] = __builtin_amdgcn_mfma_f32_32x32x16_bf16(ah, bl, acc[i], 0, 0, 0);
        acc[i] = __builtin_amdgcn_mfma_f32_32x32x16_bf16(al, bh, acc[i], 0, 0, 0);
      }
    }
    __syncthreads();
  }

  float* ob = out + (size_t)b * 192 * 65536 + n0 + wc32 + l31;
#pragma unroll
  for (int i = 0; i < 3; ++i)
#pragma unroll
    for (int g = 0; g < 16; ++g) {
      const int row = wr + i * 32 + (g & 3) + 8 * (g >> 2) + 4 * (lane >> 5);
      ob[(size_t)row * 65536] = acc[i][g];
    }
}

// ---------------------------------------------------------------- launch
extern "C" void kernel_launch(void* const* d_in, const int* in_sizes, int n_in,
                              void* d_out, int out_size, void* d_ws, size_t ws_size,
                              hipStream_t stream) {
  const float* x    = (const float*)d_in[0];
  const float* wqkv = (const float*)d_in[1];
  const float* wout = (const float*)d_in[2];
  const float* temp = (const float*)d_in[3];
  float* out = (float*)d_out;
  float* ws  = (float*)d_ws;

  // ws: slabs | S | M | Phi | Plo  (same 77.3MB footprint proven in r2/r3)
  const size_t slabs_fl = (size_t)128 * 4 * 36864;      // 18,874,368
  float* spart = ws;
  float* S    = ws + slabs_fl;                          // 147456 floats
  float* Mbuf = S + 147456;                             // 147456
  unsigned short* Phi = (unsigned short*)(Mbuf + 147456);  // 147456 ushorts
  unsigned short* Plo = Phi + 147456;                      // 147456 ushorts

  k1_mfma<<<dim3(128, 4), 256, 0, stream>>>(x, spart);
  kreduce<<<dim3(144, 4), 256, 0, stream>>>(spart, S);
  k2a_softmax_m<<<dim3(8, 4), 256, 0, stream>>>(S, wqkv, temp, wout, Mbuf, 1);
  k2b_p<<<dim3(24, 4), 256, 0, stream>>>(Mbuf, wqkv, Phi, Plo);
  k3_mfma<<<dim3(512, 4), 512, 0, stream>>>(Phi, Plo, x, out);
}